// Round 1
// baseline (454.459 us; speedup 1.0000x reference)
//
#include <hip/hip_runtime.h>
#include <cmath>

#define B_ 256
#define G_ 2048
#define F_ 128
#define RNN_ 512
#define K_ 128

// ---------------------------------------------------------------------------
// Kernel 1: scorer_norm[b][f] = tanh(h_t[b]·W[:,f] + b_map[f]) / ||tanh row||
// 256 blocks (one per b) x 128 threads (one per f).
// ---------------------------------------------------------------------------
__global__ __launch_bounds__(128) void k_scorer(const float* __restrict__ h_t,
                                                const float* __restrict__ W,
                                                const float* __restrict__ b_map,
                                                float* __restrict__ scorer_norm) {
    __shared__ float h[RNN_];
    __shared__ float red[128];
    const int b = blockIdx.x;
    const int f = threadIdx.x;
    for (int i = f; i < RNN_; i += 128) h[i] = h_t[b * RNN_ + i];
    __syncthreads();
    float acc = 0.f;
#pragma unroll 8
    for (int r = 0; r < RNN_; ++r) acc += h[r] * W[r * F_ + f];
    const float t = tanhf(acc + b_map[f]);
    red[f] = t * t;
    __syncthreads();
    for (int s = 64; s > 0; s >>= 1) {
        if (f < s) red[f] += red[f + s];
        __syncthreads();
    }
    const float norm = sqrtf(red[0]);
    scorer_norm[b * F_ + f] = t / norm;
}

// ---------------------------------------------------------------------------
// Kernel 2: scores[b][g] = node_embs[b][g][:] · scorer_norm[b][:] + mask[b][g]
// grid (G/64, B), 256 threads. Per 64-lane wave: 2 rows/pass, 32 lanes/row,
// float4 per lane (1KB coalesced per wave instruction), shfl reduce in halves.
// ---------------------------------------------------------------------------
__global__ __launch_bounds__(256) void k_scores(const float* __restrict__ node,
                                                const float* __restrict__ mask,
                                                const float* __restrict__ scorer_norm,
                                                float* __restrict__ scores) {
    const int b = blockIdx.y;
    const int gbase = blockIdx.x * 64;
    const int tid = threadIdx.x;
    const int wave = tid >> 6;
    const int lane = tid & 63;
    const int half = lane >> 5;  // 0 or 1: which row of the pair
    const int l32 = lane & 31;

    const float4 s4 = ((const float4*)(scorer_norm + b * F_))[l32];
    const float4* nb = (const float4*)(node + (size_t)b * G_ * F_);
    const int rowbase = gbase + wave * 16;
#pragma unroll
    for (int p = 0; p < 8; ++p) {
        const int g = rowbase + p * 2 + half;
        const float4 e = nb[(size_t)g * 32 + l32];
        float part = e.x * s4.x + e.y * s4.y + e.z * s4.z + e.w * s4.w;
        part += __shfl_xor(part, 16);
        part += __shfl_xor(part, 8);
        part += __shfl_xor(part, 4);
        part += __shfl_xor(part, 2);
        part += __shfl_xor(part, 1);
        if (l32 == 0) scores[b * G_ + g] = part + mask[b * G_ + g];
    }
}

// ---------------------------------------------------------------------------
// Kernel 3: per-b top-128 (bitonic full sort, jax tie-break), log-softmax
// policy score, gather+transpose+tanh-scale. 256 blocks x 512 threads.
// LDS: 8K scores + 16K keys + 16.9K tile + ~3.5K misc = ~45 KB.
// ---------------------------------------------------------------------------
__global__ __launch_bounds__(512) void k_topk(const float* __restrict__ node,
                                              const float* __restrict__ scores,
                                              float* __restrict__ out,
                                              float* __restrict__ policy) {
    __shared__ float sc[G_];
    __shared__ unsigned long long keys[G_];
    __shared__ float tile[K_][33];
    __shared__ float tanhv[K_];
    __shared__ int idxk[K_];
    __shared__ float valk[K_];
    __shared__ float red[512];

    const int b = blockIdx.x;
    const int tid = threadIdx.x;

    // load scores, build sortable keys: monotone-float<<32 | (2047 - idx)
    for (int i = tid; i < G_; i += 512) {
        const float v = scores[b * G_ + i];
        sc[i] = v;
        unsigned u = __float_as_uint(v);
        u = (u & 0x80000000u) ? ~u : (u | 0x80000000u);
        keys[i] = ((unsigned long long)u << 32) | (unsigned)(G_ - 1 - i);
    }
    __syncthreads();

    // ascending bitonic sort of 2048 u64 keys
    for (int k = 2; k <= G_; k <<= 1) {
        for (int j = k >> 1; j > 0; j >>= 1) {
            for (int i = tid; i < G_; i += 512) {
                const int ij = i ^ j;
                if (ij > i) {
                    const unsigned long long a = keys[i], c = keys[ij];
                    const bool up = ((i & k) == 0);
                    if (up ? (a > c) : (a < c)) {
                        keys[i] = c;
                        keys[ij] = a;
                    }
                }
            }
            __syncthreads();
        }
    }

    // extract top-K in descending order (tail of ascending sort)
    if (tid < K_) {
        const unsigned long long key = keys[G_ - 1 - tid];
        const int idx = G_ - 1 - (int)(unsigned)(key & 0xFFFFFFFFull);
        idxk[tid] = idx;
        const float v = sc[idx];
        valk[tid] = v;
        tanhv[tid] = tanhf(v);
    }
    __syncthreads();

    // log-sum-exp over all 2048 scores
    const float maxv = sc[G_ - 1 - (int)(unsigned)(keys[G_ - 1] & 0xFFFFFFFFull)];
    float s = 0.f;
    for (int i = tid; i < G_; i += 512) s += expf(sc[i] - maxv);
    red[tid] = s;
    __syncthreads();
    for (int o = 256; o > 0; o >>= 1) {
        if (tid < o) red[tid] += red[tid + o];
        __syncthreads();
    }
    const float lse = maxv + logf(red[0]);
    if (tid == 0) {
        float sum = 0.f;
        for (int k2 = 0; k2 < K_; ++k2) sum += valk[k2];
        policy[b] = sum * (1.0f / K_) - lse;
    }

    // gather + transpose + scale: out[b][f][k] = node[b][idx_k][f] * tanh(val_k)
    const float* nb = node + (size_t)b * G_ * F_;
    float* ob = out + (size_t)b * F_ * K_;
    for (int f0 = 0; f0 < F_; f0 += 32) {
        for (int e = tid; e < K_ * 32; e += 512) {
            const int k2 = e >> 5;
            const int f = e & 31;
            tile[k2][f] = nb[(size_t)idxk[k2] * F_ + f0 + f];
        }
        __syncthreads();
        for (int e = tid; e < 32 * K_; e += 512) {
            const int f = e >> 7;
            const int k2 = e & 127;
            ob[(size_t)(f0 + f) * K_ + k2] = tile[k2][f] * tanhv[k2];
        }
        __syncthreads();
    }
}

extern "C" void kernel_launch(void* const* d_in, const int* in_sizes, int n_in,
                              void* d_out, int out_size, void* d_ws, size_t ws_size,
                              hipStream_t stream) {
    const float* node = (const float*)d_in[0];
    const float* mask = (const float*)d_in[1];
    const float* h_t = (const float*)d_in[2];
    const float* W = (const float*)d_in[3];
    const float* bm = (const float*)d_in[4];

    float* out = (float*)d_out;                      // [B, F, K]
    float* policy = out + (size_t)B_ * F_ * K_;      // [B]

    float* scorer_norm = (float*)d_ws;               // B*F floats (128 KB)
    float* scores = scorer_norm + B_ * F_;           // B*G floats (2 MB)

    k_scorer<<<B_, 128, 0, stream>>>(h_t, W, bm, scorer_norm);
    k_scores<<<dim3(G_ / 64, B_), 256, 0, stream>>>(node, mask, scorer_norm, scores);
    k_topk<<<B_, 512, 0, stream>>>(node, scores, out, policy);
}

// Round 2
// 398.594 us; speedup vs baseline: 1.1402x; 1.1402x over previous
//
#include <hip/hip_runtime.h>
#include <cmath>

#define B_ 256
#define G_ 2048
#define F_ 128
#define RNN_ 512
#define K_ 128

// ---------------------------------------------------------------------------
// Kernel 1: scorer_norm[b][f] = tanh(h_t[b]·W[:,f] + b_map[f]) / ||tanh row||
// 256 blocks x 512 threads; r-dim split 4-way to cut the dot latency chain.
// ---------------------------------------------------------------------------
__global__ __launch_bounds__(512) void k_scorer(const float* __restrict__ h_t,
                                                const float* __restrict__ W,
                                                const float* __restrict__ b_map,
                                                float* __restrict__ scorer_norm) {
    __shared__ float h[RNN_];
    __shared__ float part[4][F_];
    __shared__ float red[F_];
    const int b = blockIdx.x;
    const int tid = threadIdx.x;
    h[tid] = h_t[b * RNN_ + tid];
    __syncthreads();
    const int f = tid & 127;
    const int qu = tid >> 7;  // 0..3 quarter of r-range
    float acc = 0.f;
    const int r0 = qu * (RNN_ / 4);
#pragma unroll 8
    for (int r = r0; r < r0 + RNN_ / 4; ++r) acc += h[r] * W[r * F_ + f];
    part[qu][f] = acc;
    __syncthreads();
    if (tid < F_) {
        const float s = part[0][tid] + part[1][tid] + part[2][tid] + part[3][tid] + b_map[tid];
        const float t = tanhf(s);
        part[0][tid] = t;
        red[tid] = t * t;
    }
    __syncthreads();
    for (int s = 64; s > 0; s >>= 1) {
        if (tid < s) red[tid] += red[tid + s];
        __syncthreads();
    }
    if (tid < F_) scorer_norm[b * F_ + tid] = part[0][tid] / sqrtf(red[0]);
}

// ---------------------------------------------------------------------------
// Kernel 2: scores[b][g] = node_embs[b][g][:] · scorer_norm[b][:] + mask[b][g]
// grid (G/64, B), 256 threads. 32 lanes x float4 per row = 1KB/wave instr.
// ---------------------------------------------------------------------------
__global__ __launch_bounds__(256) void k_scores(const float* __restrict__ node,
                                                const float* __restrict__ mask,
                                                const float* __restrict__ scorer_norm,
                                                float* __restrict__ scores) {
    const int b = blockIdx.y;
    const int gbase = blockIdx.x * 64;
    const int tid = threadIdx.x;
    const int wave = tid >> 6;
    const int lane = tid & 63;
    const int half = lane >> 5;
    const int l32 = lane & 31;

    const float4 s4 = ((const float4*)(scorer_norm + b * F_))[l32];
    const float4* nb = (const float4*)(node + (size_t)b * G_ * F_);
    const int rowbase = gbase + wave * 16;
#pragma unroll
    for (int p = 0; p < 8; ++p) {
        const int g = rowbase + p * 2 + half;
        const float4 e = nb[(size_t)g * 32 + l32];
        float part = e.x * s4.x + e.y * s4.y + e.z * s4.z + e.w * s4.w;
        part += __shfl_xor(part, 16);
        part += __shfl_xor(part, 8);
        part += __shfl_xor(part, 4);
        part += __shfl_xor(part, 2);
        part += __shfl_xor(part, 1);
        if (l32 == 0) scores[b * G_ + g] = part + mask[b * G_ + g];
    }
}

// ---------------------------------------------------------------------------
// Kernel 3: per-b exact top-128 via u64 radix-select (value || 2047-idx),
// sort only the 128 winners, log-softmax policy, gather+transpose+scale.
// 256 blocks x 512 threads. LDS ~54 KB.
// ---------------------------------------------------------------------------
__global__ __launch_bounds__(512) void k_topk(const float* __restrict__ node,
                                              const float* __restrict__ scores,
                                              float* __restrict__ out,
                                              float* __restrict__ policy) {
    __shared__ float sc[G_];
    __shared__ unsigned long long keys[G_];
    __shared__ unsigned hist[8][256];
    __shared__ unsigned long long win[K_];
    __shared__ float tile[K_][33];
    __shared__ float tanhv[K_];
    __shared__ int idxk[K_];
    __shared__ float valk[K_];
    __shared__ float red[512];
    __shared__ unsigned long long prefix_sh;
    __shared__ int need_sh;
    __shared__ int cnt;

    const int b = blockIdx.x;
    const int tid = threadIdx.x;
    const int w = tid >> 6;

    // build sortable keys: monotone-float<<32 | (2047 - idx)  (all distinct)
    for (int i = tid; i < G_; i += 512) {
        const float v = scores[b * G_ + i];
        sc[i] = v;
        unsigned u = __float_as_uint(v);
        u = (u & 0x80000000u) ? ~u : (u | 0x80000000u);
        keys[i] = ((unsigned long long)u << 32) | (unsigned)(G_ - 1 - i);
    }
    if (tid == 0) cnt = 0;
    __syncthreads();

    // ---- radix select: find T = exact 128th-largest u64 key ----
    unsigned long long prefix = 0;
    int need = K_;
    for (int shift = 56; shift >= 0; shift -= 8) {
        // zero privatized histograms
        for (int i = tid; i < 8 * 256; i += 512) ((unsigned*)hist)[i] = 0u;
        __syncthreads();
        const unsigned long long hi_mask =
            (shift == 56) ? 0ull : (~0ull << (shift + 8));
        for (int i = tid; i < G_; i += 512) {
            const unsigned long long key = keys[i];
            if ((key & hi_mask) == prefix)
                atomicAdd(&hist[w][(unsigned)(key >> shift) & 255u], 1u);
        }
        __syncthreads();
        if (tid < 256) {
            unsigned s = 0;
#pragma unroll
            for (int ww = 0; ww < 8; ++ww) s += hist[ww][tid];
            hist[0][tid] = s;
        }
        __syncthreads();
        // wave 0: suffix-scan over 256 digits, pick the digit holding rank `need`
        if (tid < 64) {
            const int L = tid;
            const unsigned h0 = hist[0][4 * L + 0];
            const unsigned h1 = hist[0][4 * L + 1];
            const unsigned h2 = hist[0][4 * L + 2];
            const unsigned h3 = hist[0][4 * L + 3];
            const unsigned s3 = h3, s2 = h2 + s3, s1 = h1 + s2, s0 = h0 + s1;
            unsigned S = s0;  // inclusive suffix scan of lane totals
            for (int off = 1; off < 64; off <<= 1) {
                const unsigned t = __shfl_down(S, off);
                if (L + off < 64) S += t;
            }
            unsigned Snext = __shfl_down(S, 1);
            if (L == 63) Snext = 0;
            const unsigned un = (unsigned)need;
            const unsigned suf0 = Snext + s0, suf1 = Snext + s1;
            const unsigned suf2 = Snext + s2, suf3 = Snext + s3, suf4 = Snext;
            int d = -1;
            unsigned sufd1 = 0;
            if (suf0 >= un && suf1 < un) { d = 4 * L + 0; sufd1 = suf1; }
            else if (suf1 >= un && suf2 < un) { d = 4 * L + 1; sufd1 = suf2; }
            else if (suf2 >= un && suf3 < un) { d = 4 * L + 2; sufd1 = suf3; }
            else if (suf3 >= un && suf4 < un) { d = 4 * L + 3; sufd1 = suf4; }
            if (d >= 0) {
                prefix_sh = prefix | ((unsigned long long)(unsigned)d << shift);
                need_sh = need - (int)sufd1;
            }
        }
        __syncthreads();
        prefix = prefix_sh;
        need = need_sh;
    }
    const unsigned long long T = prefix;  // exactly 128 keys are >= T

    // ---- compact winners (unordered) ----
    for (int i = tid; i < G_; i += 512) {
        const unsigned long long key = keys[i];
        if (key >= T) {
            const int p = atomicAdd(&cnt, 1);
            win[p] = key;
        }
    }
    __syncthreads();

    // ---- ascending bitonic sort of the 128 winners ----
    for (int k = 2; k <= K_; k <<= 1) {
        for (int j = k >> 1; j > 0; j >>= 1) {
            if (tid < K_) {
                const int i = tid;
                const int ij = i ^ j;
                if (ij > i) {
                    const unsigned long long a = win[i], c = win[ij];
                    const bool up = ((i & k) == 0);
                    if (up ? (a > c) : (a < c)) {
                        win[i] = c;
                        win[ij] = a;
                    }
                }
            }
            __syncthreads();
        }
    }

    // extract in descending order
    if (tid < K_) {
        const unsigned long long key = win[K_ - 1 - tid];
        const int idx = G_ - 1 - (int)(unsigned)(key & 0xFFFFFFFFull);
        idxk[tid] = idx;
        const float v = sc[idx];
        valk[tid] = v;
        tanhv[tid] = tanhf(v);
    }
    __syncthreads();

    // log-sum-exp over all 2048 scores (max = top-1 value)
    const float maxv = valk[0];
    float s = 0.f;
    for (int i = tid; i < G_; i += 512) s += expf(sc[i] - maxv);
    red[tid] = s;
    __syncthreads();
    for (int o = 256; o > 0; o >>= 1) {
        if (tid < o) red[tid] += red[tid + o];
        __syncthreads();
    }
    const float lse = maxv + logf(red[0]);
    if (tid == 0) {
        float sum = 0.f;
        for (int k2 = 0; k2 < K_; ++k2) sum += valk[k2];
        policy[b] = sum * (1.0f / K_) - lse;
    }

    // gather + transpose + scale: out[b][f][k] = node[b][idx_k][f] * tanh(val_k)
    const float* nb = node + (size_t)b * G_ * F_;
    float* ob = out + (size_t)b * F_ * K_;
    for (int f0 = 0; f0 < F_; f0 += 32) {
        // 128 rows x 8 float4 loads (coalesced 128B row segments)
        for (int e = tid; e < K_ * 8; e += 512) {
            const int k2 = e >> 3;
            const int q = e & 7;
            const float4 v = *(const float4*)(nb + (size_t)idxk[k2] * F_ + f0 + 4 * q);
            tile[k2][4 * q + 0] = v.x;
            tile[k2][4 * q + 1] = v.y;
            tile[k2][4 * q + 2] = v.z;
            tile[k2][4 * q + 3] = v.w;
        }
        __syncthreads();
        for (int e = tid; e < 32 * K_; e += 512) {
            const int f = e >> 7;
            const int k2 = e & 127;
            ob[(size_t)(f0 + f) * K_ + k2] = tile[k2][f] * tanhv[k2];
        }
        __syncthreads();
    }
}

extern "C" void kernel_launch(void* const* d_in, const int* in_sizes, int n_in,
                              void* d_out, int out_size, void* d_ws, size_t ws_size,
                              hipStream_t stream) {
    const float* node = (const float*)d_in[0];
    const float* mask = (const float*)d_in[1];
    const float* h_t = (const float*)d_in[2];
    const float* W = (const float*)d_in[3];
    const float* bm = (const float*)d_in[4];

    float* out = (float*)d_out;                  // [B, F, K]
    float* policy = out + (size_t)B_ * F_ * K_;  // [B]

    float* scorer_norm = (float*)d_ws;           // B*F floats
    float* scores = scorer_norm + B_ * F_;       // B*G floats

    k_scorer<<<B_, 512, 0, stream>>>(h_t, W, bm, scorer_norm);
    k_scores<<<dim3(G_ / 64, B_), 256, 0, stream>>>(node, mask, scorer_norm, scores);
    k_topk<<<B_, 512, 0, stream>>>(node, scores, out, policy);
}